// Round 10
// baseline (1385.703 us; speedup 1.0000x reference)
//
#include <hip/hip_runtime.h>
#include <math.h>

#define D_MODEL 1024
#define NHEAD   16
#define HDIM    64
#define HID     2730
#define HID_PAD 2816          // 22 * 128
#define SEQ     2048
#define BATCH   2
#define NTOK    (BATCH * SEQ)   // 4096
#define QKG     3072            // packed q|k|g row stride (elements)

typedef __attribute__((ext_vector_type(8))) short bf16x8;
typedef __attribute__((ext_vector_type(4))) float f32x4;
typedef __attribute__((ext_vector_type(4))) short s16x4;

// fp32 -> bf16 round-to-nearest-even
static __device__ inline short f2bf(float f)
{
    union { float f; unsigned int u; } c; c.f = f;
    unsigned int r = c.u + 0x7FFFu + ((c.u >> 16) & 1u);
    return (short)(r >> 16);
}
static __device__ inline float bf2f(short s)
{
    union { unsigned int u; float f; } c;
    c.u = ((unsigned int)(unsigned short)s) << 16;
    return c.f;
}

// async global->LDS, 16B per lane; lds dest = wave-uniform base + lane*16
#define GLD16(gsrc, ldst) \
    __builtin_amdgcn_global_load_lds((const __attribute__((address_space(1))) void*)(gsrc), \
                                     (__attribute__((address_space(3))) void*)(ldst), 16, 0, 0)

// ---------------------------------------------------------------------------
// LayerNorm: one block (256 threads) per row of 1024, fp32 in -> bf16 out
// ---------------------------------------------------------------------------
__global__ void ln_kernel(const float* __restrict__ x,
                          const float* __restrict__ w,
                          const float* __restrict__ b,
                          short* __restrict__ out,
                          float eps)
{
    int row = blockIdx.x;
    int t = threadIdx.x;               // 0..255
    const float4* xr = (const float4*)(x + (size_t)row * D_MODEL);
    float4 v = xr[t];
    float s  = v.x + v.y + v.z + v.w;
    float sq = v.x * v.x + v.y * v.y + v.z * v.z + v.w * v.w;
#pragma unroll
    for (int off = 32; off > 0; off >>= 1) {
        s  += __shfl_xor(s, off);
        sq += __shfl_xor(sq, off);
    }
    __shared__ float ss[4], ssq[4];
    int wave = t >> 6;
    if ((t & 63) == 0) { ss[wave] = s; ssq[wave] = sq; }
    __syncthreads();
    s  = ss[0] + ss[1] + ss[2] + ss[3];
    sq = ssq[0] + ssq[1] + ssq[2] + ssq[3];
    float mu  = s * (1.0f / D_MODEL);
    float var = sq * (1.0f / D_MODEL) - mu * mu;
    float inv = rsqrtf(var + eps);
    float4 wv = ((const float4*)w)[t];
    float4 bv = ((const float4*)b)[t];
    s16x4 o;
    o.x = f2bf((v.x - mu) * inv * wv.x + bv.x);
    o.y = f2bf((v.y - mu) * inv * wv.y + bv.y);
    o.z = f2bf((v.z - mu) * inv * wv.z + bv.z);
    o.w = f2bf((v.w - mu) * inv * wv.w + bv.w);
    *(s16x4*)(out + (size_t)row * D_MODEL + 4 * t) = o;
}

// ---------------------------------------------------------------------------
// Merged transpose+cast: all 8 weight jobs in ONE launch.
// ---------------------------------------------------------------------------
struct TJob {
    const float* src;
    short* dst;
    int ldsrc, coloff, nvalid, kvalid, KPAD, NPAD;
};
struct TJobs { TJob j[8]; };

__global__ __launch_bounds__(256) void transpose_all(TJobs jobs)
{
    TJob jb = jobs.j[blockIdx.z];
    int k0 = blockIdx.x * 64, n0 = blockIdx.y * 64;
    if (k0 >= jb.KPAD || n0 >= jb.NPAD) return;
    __shared__ float tile[64][65];
    int t = threadIdx.x;
    {
        int kk = t >> 2, np = (t & 3) << 4;
        int k = k0 + kk;
        bool kok = k < jb.kvalid;
        const float* srow = jb.src + (size_t)k * jb.ldsrc + jb.coloff + n0 + np;
#pragma unroll
        for (int i = 0; i < 16; ++i) {
            int n = n0 + np + i;
            tile[kk][np + i] = (kok && n < jb.nvalid) ? srow[i] : 0.0f;
        }
    }
    __syncthreads();
    {
        int nn = t >> 2, kp = (t & 3) << 4;
        short* drow = jb.dst + (size_t)(n0 + nn) * jb.KPAD + k0 + kp;
#pragma unroll
        for (int v4 = 0; v4 < 4; ++v4) {
            s16x4 o;
            o.x = f2bf(tile[kp + v4 * 4 + 0][nn]);
            o.y = f2bf(tile[kp + v4 * 4 + 1][nn]);
            o.z = f2bf(tile[kp + v4 * 4 + 2][nn]);
            o.w = f2bf(tile[kp + v4 * 4 + 3][nn]);
            *(s16x4*)(drow + v4 * 4) = o;
        }
    }
}

// ---------------------------------------------------------------------------
// bf16 MFMA GEMM core (m97 structure + dbuf prefetch), 128x128, BK=32.
// Used by proj_kernel (both operands via LDS).
// ---------------------------------------------------------------------------
template<int EPI>
static __device__ __forceinline__ void gemm_core(
        const short* __restrict__ A, int lda,
        const short* __restrict__ Bt,
        const float* __restrict__ bias,
        const float* __restrict__ R, int ldr,
        void* __restrict__ C, int ldc, int K, int bm, int bn,
        short (*As)[4096], short (*Bs)[4096])
{
    int t = threadIdx.x;
    int w = t >> 6;
    int lane = t & 63;
    int quad = lane >> 4;
    int l15  = lane & 15;

    const short* gA0 = A  + (size_t)(bm + (t >> 2)) * lda + ((t & 3) << 3);
    const short* gA1 = gA0 + (size_t)64 * lda;
    const short* gB0 = Bt + (size_t)(bn + (t >> 2)) * K + ((t & 3) << 3);
    const short* gB1 = gB0 + (size_t)64 * K;
    int wb = w << 9;   // wave staging base (shorts)

    int wr = (w >> 1) * 64;
    int wc = (w & 1) * 64;

    f32x4 acc[4][4];
#pragma unroll
    for (int i = 0; i < 4; ++i)
#pragma unroll
        for (int j = 0; j < 4; ++j) acc[i][j] = (f32x4){0.f, 0.f, 0.f, 0.f};

    GLD16(gA0, &As[0][wb]);
    GLD16(gA1, &As[0][2048 + wb]);
    GLD16(gB0, &Bs[0][wb]);
    GLD16(gB1, &Bs[0][2048 + wb]);

    for (int k0 = 0; k0 < K; k0 += 32) {
        int cur = (k0 >> 5) & 1;
        __syncthreads();
        int k1 = k0 + 32;
        if (k1 < K) {
            GLD16(gA0 + k1, &As[cur ^ 1][wb]);
            GLD16(gA1 + k1, &As[cur ^ 1][2048 + wb]);
            GLD16(gB0 + k1, &Bs[cur ^ 1][wb]);
            GLD16(gB1 + k1, &Bs[cur ^ 1][2048 + wb]);
        }
        bf16x8 af[4], bfr[4];
#pragma unroll
        for (int i = 0; i < 4; ++i)
            af[i] = *(const bf16x8*)(&As[cur][(wr + i * 16 + l15) * 32 + quad * 8]);
#pragma unroll
        for (int j = 0; j < 4; ++j)
            bfr[j] = *(const bf16x8*)(&Bs[cur][(wc + j * 16 + l15) * 32 + quad * 8]);
#pragma unroll
        for (int i = 0; i < 4; ++i)
#pragma unroll
            for (int j = 0; j < 4; ++j)
                acc[i][j] = __builtin_amdgcn_mfma_f32_16x16x32_bf16(af[i], bfr[j], acc[i][j], 0, 0, 0);
    }

#pragma unroll
    for (int i = 0; i < 4; ++i) {
        int gr = bm + wr + i * 16 + quad * 4;
#pragma unroll
        for (int j = 0; j < 4; ++j) {
            int gc = bn + wc + j * 16 + l15;
#pragma unroll
            for (int r = 0; r < 4; ++r) {
                float val = acc[i][j][r];
                size_t idx = (size_t)(gr + r) * ldc + gc;
                if (EPI == 0) {
                    ((short*)C)[idx] = f2bf(val);
                } else if (EPI == 1) {
                    ((float*)C)[idx] = val + R[(size_t)(gr + r) * ldr + gc];
                } else {
                    ((float*)C)[idx] = val + bias[gc] + R[(size_t)(gr + r) * ldr + gc];
                }
            }
        }
    }
}

// merged q|k|g + v^T projection: 1024 blocks in one launch
__global__ __launch_bounds__(256, 4) void proj_kernel(
        const short* __restrict__ xn,
        const short* __restrict__ qkgT,
        short* __restrict__ qkg,
        const short* __restrict__ wvT,
        short* __restrict__ vT)
{
    __shared__ short As[2][4096];
    __shared__ short Bs[2][4096];
    int id = blockIdx.x;
    if (id < 768) {
        int bm = (id & 31) * 128, bn = (id >> 5) * 128;
        gemm_core<0>(xn, D_MODEL, qkgT, nullptr, nullptr, 0, qkg, QKG, D_MODEL, bm, bn, As, Bs);
    } else {
        int i2 = id - 768;
        int bn = (i2 & 31) * 128, bm = (i2 >> 5) * 128;
        gemm_core<0>(wvT, D_MODEL, xn, nullptr, nullptr, 0, vT, NTOK, D_MODEL, bm, bn, As, Bs);
    }
}

// ---------------------------------------------------------------------------
// 128x64-tile GEMM with DIRECT global->VGPR B-fragment loads (weight operand
// is L2-hot; frag = 16 x 64B segments/wave). Only A goes through LDS ->
// halves LDS-pipe traffic. Register-dbuf B one chunk ahead.
// ---------------------------------------------------------------------------
template<int EPI>
__global__ __launch_bounds__(256, 4) void gemm_n64(
        const short* __restrict__ A, int lda,
        const short* __restrict__ Bt,
        const float* __restrict__ bias,
        const float* __restrict__ R, int ldr,
        void* __restrict__ C, int ldc, int K)
{
    __shared__ short As[2][4096];
    int bm = blockIdx.x * 128;          // row tile fastest
    int bn = blockIdx.y * 64;
    int t = threadIdx.x;
    int w = t >> 6;
    int lane = t & 63;
    int quad = lane >> 4;
    int l15  = lane & 15;

    const short* gA0 = A + (size_t)(bm + (t >> 2)) * lda + ((t & 3) << 3);
    const short* gA1 = gA0 + (size_t)64 * lda;
    int wb = w << 9;

    int wr = (w >> 1) * 64;
    int wc = (w & 1) * 32;

    // direct B frag pointers: row bn+wc+j*16+l15, col quad*8 (+k)
    const short* pB = Bt + (size_t)(bn + wc + l15) * K + quad * 8;

    f32x4 acc[4][2];
#pragma unroll
    for (int i = 0; i < 4; ++i)
#pragma unroll
        for (int j = 0; j < 2; ++j) acc[i][j] = (f32x4){0.f, 0.f, 0.f, 0.f};

    bf16x8 bfr[2][2];
#pragma unroll
    for (int j = 0; j < 2; ++j)
        bfr[0][j] = *(const bf16x8*)(pB + (size_t)j * 16 * K);
    GLD16(gA0, &As[0][wb]);
    GLD16(gA1, &As[0][2048 + wb]);

#pragma unroll 4
    for (int k0 = 0; k0 < K; k0 += 32) {
        int p = (k0 >> 5) & 1;
        __syncthreads();
        int k1 = k0 + 32;
        if (k1 < K) {
            GLD16(gA0 + k1, &As[p ^ 1][wb]);
            GLD16(gA1 + k1, &As[p ^ 1][2048 + wb]);
#pragma unroll
            for (int j = 0; j < 2; ++j)
                bfr[p ^ 1][j] = *(const bf16x8*)(pB + (size_t)j * 16 * K + k1);
        }
        bf16x8 af[4];
#pragma unroll
        for (int i = 0; i < 4; ++i)
            af[i] = *(const bf16x8*)(&As[p][(wr + i * 16 + l15) * 32 + quad * 8]);
#pragma unroll
        for (int i = 0; i < 4; ++i)
#pragma unroll
            for (int j = 0; j < 2; ++j)
                acc[i][j] = __builtin_amdgcn_mfma_f32_16x16x32_bf16(af[i], bfr[p][j], acc[i][j], 0, 0, 0);
    }

#pragma unroll
    for (int i = 0; i < 4; ++i) {
        int gr = bm + wr + i * 16 + quad * 4;
#pragma unroll
        for (int j = 0; j < 2; ++j) {
            int gc = bn + wc + j * 16 + l15;
#pragma unroll
            for (int r = 0; r < 4; ++r) {
                float val = acc[i][j][r];
                size_t idx = (size_t)(gr + r) * ldc + gc;
                if (EPI == 0) {
                    ((short*)C)[idx] = f2bf(val);
                } else if (EPI == 1) {
                    ((float*)C)[idx] = val + R[(size_t)(gr + r) * ldr + gc];
                } else {
                    ((float*)C)[idx] = val + bias[gc] + R[(size_t)(gr + r) * ldr + gc];
                }
            }
        }
    }
}

// ---------------------------------------------------------------------------
// Fused SwiGLU-in GEMM: A via LDS, Ba/Bb DIRECT global->VGPR (reg-dbuf).
// 128x64 tile; LDS 16 KB.
// ---------------------------------------------------------------------------
__global__ __launch_bounds__(256, 3) void mlp_fused(
        const short* __restrict__ A,       // [NTOK][1024] bf16
        const short* __restrict__ w_inT,   // [2*HID_PAD][1024] bf16
        const float* __restrict__ b_in,    // [2*HID]
        short* __restrict__ hm)            // [NTOK][HID_PAD] bf16
{
    __shared__ short As[2][4096];
    const int K = D_MODEL;
    int bm = blockIdx.x * 128;            // row tile fastest
    int bn = blockIdx.y * 64;
    int t = threadIdx.x;
    int w = t >> 6;
    int lane = t & 63;
    int quad = lane >> 4;
    int l15  = lane & 15;

    const short* gA0 = A + (size_t)(bm + (t >> 2)) * K + ((t & 3) << 3);
    const short* gA1 = gA0 + (size_t)64 * K;
    int wb = w << 9;

    int wr = (w >> 1) * 64;
    int wc = (w & 1) * 32;

    const short* pBa = w_inT + (size_t)(bn + wc + l15) * K + quad * 8;
    const short* pBb = pBa + (size_t)HID_PAD * K;

    f32x4 acca[4][2], accb[4][2];
#pragma unroll
    for (int i = 0; i < 4; ++i)
#pragma unroll
        for (int j = 0; j < 2; ++j) {
            acca[i][j] = (f32x4){0.f, 0.f, 0.f, 0.f};
            accb[i][j] = (f32x4){0.f, 0.f, 0.f, 0.f};
        }

    bf16x8 ba[2][2], bb[2][2];
#pragma unroll
    for (int j = 0; j < 2; ++j) {
        ba[0][j] = *(const bf16x8*)(pBa + (size_t)j * 16 * K);
        bb[0][j] = *(const bf16x8*)(pBb + (size_t)j * 16 * K);
    }
    GLD16(gA0, &As[0][wb]);
    GLD16(gA1, &As[0][2048 + wb]);

#pragma unroll 4
    for (int k0 = 0; k0 < K; k0 += 32) {
        int p = (k0 >> 5) & 1;
        __syncthreads();
        int k1 = k0 + 32;
        if (k1 < K) {
            GLD16(gA0 + k1, &As[p ^ 1][wb]);
            GLD16(gA1 + k1, &As[p ^ 1][2048 + wb]);
#pragma unroll
            for (int j = 0; j < 2; ++j) {
                ba[p ^ 1][j] = *(const bf16x8*)(pBa + (size_t)j * 16 * K + k1);
                bb[p ^ 1][j] = *(const bf16x8*)(pBb + (size_t)j * 16 * K + k1);
            }
        }
        bf16x8 af[4];
#pragma unroll
        for (int i = 0; i < 4; ++i)
            af[i] = *(const bf16x8*)(&As[p][(wr + i * 16 + l15) * 32 + quad * 8]);
#pragma unroll
        for (int i = 0; i < 4; ++i)
#pragma unroll
            for (int j = 0; j < 2; ++j) {
                acca[i][j] = __builtin_amdgcn_mfma_f32_16x16x32_bf16(af[i], ba[p][j], acca[i][j], 0, 0, 0);
                accb[i][j] = __builtin_amdgcn_mfma_f32_16x16x32_bf16(af[i], bb[p][j], accb[i][j], 0, 0, 0);
            }
    }

#pragma unroll
    for (int i = 0; i < 4; ++i) {
        int gr = bm + wr + i * 16 + quad * 4;
#pragma unroll
        for (int j = 0; j < 2; ++j) {
            int gc = bn + wc + j * 16 + l15;
            bool ok = gc < HID;
            float bia = ok ? b_in[gc] : 0.0f;
            float bib = ok ? b_in[HID + gc] : 0.0f;
#pragma unroll
            for (int r = 0; r < 4; ++r) {
                float a  = acca[i][j][r] + bia;
                float bv = accb[i][j][r] + bib;
                float val = ok ? a * (bv / (1.0f + expf(-bv))) : 0.0f;
                hm[(size_t)(gr + r) * HID_PAD + gc] = f2bf(val);
            }
        }
    }
}

// ---------------------------------------------------------------------------
// MFMA retention + groupnorm + silu gate. 512 threads (8 waves), 128 q-rows.
// ---------------------------------------------------------------------------
#define PSTR 72   // ps row stride in shorts

__global__ __launch_bounds__(512) void retention_mfma(
        const short* __restrict__ qkg,
        const short* __restrict__ vT,
        short* __restrict__ rg)
{
    int qb = (int)gridDim.x - 1 - (int)blockIdx.x;   // heavy blocks first
    int h  = blockIdx.y;
    int b  = blockIdx.z;

    __shared__ short ks[2][4096];         // [buf][d-chunk(2)][64 t][32 d]
    __shared__ short vt[2][4096];         // [buf][t-chunk(2)][64 d][32 t]
    __shared__ short ps[8][16 * PSTR];    // per-wave P tile

    int tid  = threadIdx.x;
    int w    = tid >> 6;
    int lane = tid & 63;
    int quad = lane >> 4;
    int l15  = lane & 15;

    float log2g = log1pf(-exp2f(-5.0f - (float)h)) * 1.4426950408889634f;
    int hcol = h * HDIM;
    int s0 = qb * 128;
    size_t tok0 = (size_t)b * SEQ;

    int sch  = tid >> 8;
    int srow = (tid >> 2) & 63;
    int sp8  = (tid & 3) << 3;
    const short* kbase  = qkg + (tok0 + srow) * QKG + 1024 + hcol + sch * 32 + sp8;
    const short* vtbase = vT + (size_t)(hcol + srow) * NTOK + tok0 + sch * 32 + sp8;
    int lb = tid << 3;

    const short* qrow = qkg + (tok0 + s0 + w * 16 + l15) * QKG + hcol;
    bf16x8 qa0 = *(const bf16x8*)(qrow + quad * 8);
    bf16x8 qa1 = *(const bf16x8*)(qrow + 32 + quad * 8);

    float colfac[4];
#pragma unroll
    for (int tile = 0; tile < 4; ++tile)
        colfac[tile] = exp2f(-(float)(tile * 16 + l15) * log2g) * 0.125f;

    f32x4 oacc[4];
#pragma unroll
    for (int i = 0; i < 4; ++i) oacc[i] = (f32x4){0.f, 0.f, 0.f, 0.f};

    int sbase = s0 + w * 16 + quad * 4;
    int tmax = 2 * qb + 1;

    GLD16(kbase, &ks[0][lb]);
    GLD16(vtbase, &vt[0][lb]);

    for (int tb = 0; tb <= tmax; ++tb) {
        int cur = tb & 1;
        __syncthreads();
        if (tb < tmax) {
            GLD16(kbase + (size_t)(tb + 1) * 64 * QKG, &ks[cur ^ 1][lb]);
            GLD16(vtbase + (tb + 1) * 64, &vt[cur ^ 1][lb]);
        }

        f32x4 sacc[4];
#pragma unroll
        for (int i = 0; i < 4; ++i) sacc[i] = (f32x4){0.f, 0.f, 0.f, 0.f};
#pragma unroll
        for (int tile = 0; tile < 4; ++tile) {
            bf16x8 kb0 = *(const bf16x8*)(&ks[cur][(tile * 16 + l15) * 32 + quad * 8]);
            bf16x8 kb1 = *(const bf16x8*)(&ks[cur][2048 + (tile * 16 + l15) * 32 + quad * 8]);
            sacc[tile] = __builtin_amdgcn_mfma_f32_16x16x32_bf16(qa0, kb0, sacc[tile], 0, 0, 0);
            sacc[tile] = __builtin_amdgcn_mfma_f32_16x16x32_bf16(qa1, kb1, sacc[tile], 0, 0, 0);
        }

        int fbi = sbase - tb * 64;
        float rf[4];
#pragma unroll
        for (int reg = 0; reg < 4; ++reg)
            rf[reg] = exp2f((float)(fbi + reg) * log2g);

        if (tb * 64 + 63 > s0 + w * 16) {
#pragma unroll
            for (int tile = 0; tile < 4; ++tile) {
                int tt = tile * 16 + l15;
#pragma unroll
                for (int reg = 0; reg < 4; ++reg) {
                    float p = (fbi + reg >= tt) ? sacc[tile][reg] * rf[reg] * colfac[tile] : 0.0f;
                    ps[w][(quad * 4 + reg) * PSTR + tile * 16 + l15] = f2bf(p);
                }
            }
        } else {
#pragma unroll
            for (int tile = 0; tile < 4; ++tile)
#pragma unroll
                for (int reg = 0; reg < 4; ++reg)
                    ps[w][(quad * 4 + reg) * PSTR + tile * 16 + l15] =
                        f2bf(sacc[tile][reg] * (rf[reg] * colfac[tile]));
        }

#pragma unroll
        for (int ksi = 0; ksi < 2; ++ksi) {
            bf16x8 pa = *(const bf16x8*)(&ps[w][l15 * PSTR + ksi * 32 + quad * 8]);
#pragma unroll
            for (int dt = 0; dt < 4; ++dt) {
                bf16x8 vb = *(const bf16x8*)(&vt[cur][ksi * 2048 + (dt * 16 + l15) * 32 + quad * 8]);
                oacc[dt] = __builtin_amdgcn_mfma_f32_16x16x32_bf16(pa, vb, oacc[dt], 0, 0, 0);
            }
        }
    }

    float s1[4], s2[4];
#pragma unroll
    for (int reg = 0; reg < 4; ++reg) {
        s1[reg] = oacc[0][reg] + oacc[1][reg] + oacc[2][reg] + oacc[3][reg];
        s2[reg] = oacc[0][reg] * oacc[0][reg] + oacc[1][reg] * oacc[1][reg]
                + oacc[2][reg] * oacc[2][reg] + oacc[3][reg] * oacc[3][reg];
    }
#pragma unroll
    for (int off = 1; off < 16; off <<= 1) {
#pragma unroll
        for (int reg = 0; reg < 4; ++reg) {
            s1[reg] += __shfl_xor(s1[reg], off);
            s2[reg] += __shfl_xor(s2[reg], off);
        }
    }
    size_t rowtok = tok0 + s0 + w * 16 + quad * 4;
    short* obase = rg + rowtok * D_MODEL + hcol;
    const short* gbase = qkg + rowtok * QKG + 2048 + hcol;
#pragma unroll
    for (int reg = 0; reg < 4; ++reg) {
        float mu  = s1[reg] * (1.0f / 64.0f);
        float var = s2[reg] * (1.0f / 64.0f) - mu * mu;
        float inv = rsqrtf(var + 1e-6f);
#pragma unroll
        for (int dt = 0; dt < 4; ++dt) {
            float gv = bf2f(gbase[(size_t)reg * QKG + dt * 16 + l15]);
            float val = (oacc[dt][reg] - mu) * inv * (gv / (1.0f + expf(-gv)));
            obase[(size_t)reg * D_MODEL + dt * 16 + l15] = f2bf(val);
        }
    }
}

// ---------------------------------------------------------------------------
extern "C" void kernel_launch(void* const* d_in, const int* in_sizes, int n_in,
                              void* d_out, int out_size, void* d_ws, size_t ws_size,
                              hipStream_t stream)
{
    const float* x     = (const float*)d_in[0];
    const float* ln1w  = (const float*)d_in[1];
    const float* ln1b  = (const float*)d_in[2];
    const float* wq    = (const float*)d_in[3];
    const float* wk    = (const float*)d_in[4];
    const float* wv    = (const float*)d_in[5];
    const float* wg    = (const float*)d_in[6];
    const float* wo    = (const float*)d_in[7];
    const float* ln2w  = (const float*)d_in[8];
    const float* ln2b  = (const float*)d_in[9];
    const float* w_in  = (const float*)d_in[10];
    const float* b_in  = (const float*)d_in[11];
    const float* w_out = (const float*)d_in[12];
    const float* b_out = (const float*)d_in[13];
    float* out = (float*)d_out;
    char* base = (char*)d_ws;

    const size_t MB = 1u << 20;
    short* xn     = (short*)(base);            // [0,8)   [4096][1024] bf16 LN out
    short* qkgT   = (short*)(base +  8 * MB);  // [8,14)  wq|wk|wg transposed [3072][1024]
    short* wvT    = (short*)(base + 14 * MB);  // [14,16) [1024][1024]
    short* woT    = (short*)(base + 16 * MB);  // [16,18) [1024][1024]
    short* w_inT  = (short*)(base + 18 * MB);  // [18,29) [5632][1024]
    short* w_outT = (short*)(base + 29 * MB);  // [29,34.5) [1024][2816]
    short* qkg    = (short*)(base + 35 * MB);  // [35,59) [4096][3072] packed q|k|g
    short* hm     = (short*)(base + 35 * MB);  // [35,57) [4096][2816] reuses dead qkg
    short* vT     = (short*)(base + 59 * MB);  // [59,67) [1024][4096] V transposed
    short* rg     = (short*)(base + 67 * MB);  // [67,75) [4096][1024] gated retention out

    // all 8 weight transposes in one launch
    TJobs jobs;
    jobs.j[0] = { wq,    qkgT,                          1024,    0, 1024, 1024, 1024, 1024 };
    jobs.j[1] = { wk,    qkgT + 1024 * 1024,            1024,    0, 1024, 1024, 1024, 1024 };
    jobs.j[2] = { wg,    qkgT + 2 * 1024 * 1024,        1024,    0, 1024, 1024, 1024, 1024 };
    jobs.j[3] = { wv,    wvT,                           1024,    0, 1024, 1024, 1024, 1024 };
    jobs.j[4] = { wo,    woT,                           1024,    0, 1024, 1024, 1024, 1024 };
    jobs.j[5] = { w_in,  w_inT,                         2 * HID, 0,   HID, 1024, 1024, HID_PAD };
    jobs.j[6] = { w_in,  w_inT + (size_t)HID_PAD * 1024, 2 * HID, HID, HID, 1024, 1024, HID_PAD };
    jobs.j[7] = { w_out, w_outT,                        1024,    0, 1024, HID, HID_PAD, 1024 };
    transpose_all<<<dim3(44, 44, 8), 256, 0, stream>>>(jobs);

    // LN1 -> bf16
    ln_kernel<<<NTOK, 256, 0, stream>>>(x, ln1w, ln1b, xn, 1e-5f);
    // merged q|k|g + v^T projections (1024 blocks, one launch)
    proj_kernel<<<1024, 256, 0, stream>>>(xn, qkgT, qkg, wvT, vT);
    // retention + groupnorm + silu gate
    retention_mfma<<<dim3(SEQ / 128, NHEAD, BATCH), 512, 0, stream>>>(qkg, vT, rg);
    // wo projection + residual x -> out (fp32)
    gemm_n64<1><<<dim3(32, 16), 256, 0, stream>>>(rg, D_MODEL, woT, nullptr, x, D_MODEL, out, D_MODEL, D_MODEL);
    // LN2 -> bf16
    ln_kernel<<<NTOK, 256, 0, stream>>>(out, ln2w, ln2b, xn, 1e-5f);
    // fused SwiGLU-in GEMM (A via LDS, weights direct)
    mlp_fused<<<dim3(NTOK / 128, HID_PAD / 64), 256, 0, stream>>>(xn, w_inT, b_in, hm);
    // w_out GEMM + bias + residual
    gemm_n64<2><<<dim3(32, 16), 256, 0, stream>>>(hm, HID_PAD, w_outT, b_out, out, D_MODEL, out, D_MODEL, HID_PAD);
}